// Round 12
// baseline (43.518 us; speedup 1.0000x reference)
//
#include <hip/hip_runtime.h>
#include <hip/hip_fp16.h>
#include <math.h>

// Problem: B=8, H=W=256, C=10 metric channels, all fp32.
// ws layout: float[0..255] = per-block partial maxes of mass;
//            half[] at ws+1024 floats: 8*65*10 LUT of T(mass), stride 10.
// NOTE: k_main is launched TWICE this round (decomposition measurement) —
// second launch overwrites identical output; deterministic.
#define GH 256
#define GW 256
#define NC 10
#define NKNOT 65   // knots at m = k/64, k=0..64 (covers mass in [0,1])

__device__ __forceinline__ float gelu_exact(float x) {
    return 0.5f * x * (1.0f + erff(x * 0.70710678118654752f));
}
__device__ __forceinline__ float softplus_f(float x) {
    if (x > 20.f) return x;
    return log1pf(expf(x));
}

// ---- Kernel 1: blocks 0..129 build LUT (one wave per (batch,knot), 520 waves);
//      blocks 130..385 compute partial max of mass (float4 loads).
__global__ __launch_bounds__(256) void k_pre(
        const float* __restrict__ mass,
        const float* __restrict__ vel,
        const float* __restrict__ e_w1, const float* __restrict__ e_b1,
        const float* __restrict__ e_w2, const float* __restrict__ e_b2,
        const float* __restrict__ m_w1, const float* __restrict__ m_b1,
        const float* __restrict__ m_w2, const float* __restrict__ m_b2,
        const float* __restrict__ s_w1, const float* __restrict__ s_b1,
        const float* __restrict__ s_w2, const float* __restrict__ s_b2,
        float* __restrict__ ws) {
    const int tid = threadIdx.x;
    if (blockIdx.x >= 130) {  // ---- partial max over mass
        const int pb = blockIdx.x - 130;           // 0..255
        const float4* mass4 = (const float4*)mass; // 131072 float4 total
        int base = pb * 512 + tid;                 // 512 float4 per block
        float4 a = mass4[base];
        float4 c = mass4[base + 256];
        float v = fmaxf(fmaxf(fmaxf(a.x, a.y), fmaxf(a.z, a.w)),
                        fmaxf(fmaxf(c.x, c.y), fmaxf(c.z, c.w)));
        #pragma unroll
        for (int off = 32; off > 0; off >>= 1)
            v = fmaxf(v, __shfl_xor(v, off, 64));
        __shared__ float sred[4];
        if ((tid & 63) == 0) sred[tid >> 6] = v;
        __syncthreads();
        if (tid == 0)
            ws[pb] = fmaxf(fmaxf(sred[0], sred[1]), fmaxf(sred[2], sred[3]));
        return;
    }
    // ---- LUT build: wave-parallel over hidden dim
    const int wave = blockIdx.x * 4 + (tid >> 6);   // 0..519 == 8*65-1
    const int lane = tid & 63;
    if (wave >= 8 * NKNOT) return;
    const int b = wave / NKNOT, knot = wave % NKNOT;
    const float m = (float)knot * (1.0f / 64.0f);
    const float vx = vel[b * 3 + 0], vy = vel[b * 3 + 1], vz = vel[b * 3 + 2];

    float acc[10];
    {   // energy hidden unit `lane`
        float pre = m * e_w1[lane] + vx * e_w1[64 + lane] + vy * e_w1[128 + lane]
                  + vz * e_w1[192 + lane] + e_b1[lane];
        acc[0] = gelu_exact(pre) * e_w2[lane];
    }
    {   // momentum hidden unit `lane`
        float pre = m * m_w1[lane] + vx * m_w1[64 + lane] + vy * m_w1[128 + lane]
                  + vz * m_w1[192 + lane] + m_b1[lane];
        float h = gelu_exact(pre);
        acc[1] = h * m_w2[lane * 3 + 0];
        acc[2] = h * m_w2[lane * 3 + 1];
        acc[3] = h * m_w2[lane * 3 + 2];
    }
    {   // stress hidden units `lane`, `lane+64`
        float pre0 = m * s_w1[lane] + vx * s_w1[128 + lane] + vy * s_w1[256 + lane]
                   + vz * s_w1[384 + lane] + s_b1[lane];
        float pre1 = m * s_w1[64 + lane] + vx * s_w1[192 + lane] + vy * s_w1[320 + lane]
                   + vz * s_w1[448 + lane] + s_b1[64 + lane];
        float h0 = gelu_exact(pre0), h1 = gelu_exact(pre1);
        #pragma unroll
        for (int k = 0; k < 6; k++)
            acc[4 + k] = h0 * s_w2[lane * 6 + k] + h1 * s_w2[(lane + 64) * 6 + k];
    }
    #pragma unroll
    for (int c = 0; c < 10; c++) {
        float v = acc[c];
        #pragma unroll
        for (int off = 32; off > 0; off >>= 1)
            v += __shfl_xor(v, off, 64);
        acc[c] = v;
    }
    if (lane == 0) {
        __half* lut = (__half*)(ws + 1024) + (size_t)(b * NKNOT + knot) * NC;
        lut[0] = __float2half_rn(softplus_f(acc[0] + e_b2[0]));
        lut[1] = __float2half_rn(acc[1] + m_b2[0]);
        lut[2] = __float2half_rn(acc[2] + m_b2[1]);
        lut[3] = __float2half_rn(acc[3] + m_b2[2]);
        #pragma unroll
        for (int k = 0; k < 6; k++)
            lut[4 + k] = __float2half_rn(acc[4 + k] + s_b2[k]);
    }
}

// ---- Kernel 2: identical to the 27.0µs best (R8-config).
__global__ __launch_bounds__(256, 6) void k_main(const float* __restrict__ mass,
                                                 const float* __restrict__ minit,
                                                 const float* __restrict__ solver,
                                                 const float* __restrict__ ws,
                                                 float* __restrict__ out) {
    const int tid = threadIdx.x;
    const int bid = blockIdx.x;               // 0..1023
    const int b0 = bid >> 7;                  // batch
    const int p  = bid & 127;                 // pair index within batch
    const int tile_y = (p >> 3) * 16;
    const int tile_x_base = (p & 7) * 32;

    __shared__ float   s_mass[24][24];                 // 2.3 KB, halo 4
    __shared__ __half2 s_luth[NKNOT * 5];              // 1.3 KB
    __shared__ __align__(16) float2 s_met2[5][18][18]; // 13.0 KB, halo 1
    __shared__ float   s_wmax[4];

    // --- per-block fixed work (amortized over 2 tiles) ---
    {   // finalize global max (256 partials, 1/thread)
        float v = ws[tid];
        #pragma unroll
        for (int off = 32; off > 0; off >>= 1)
            v = fmaxf(v, __shfl_xor(v, off, 64));
        if ((tid & 63) == 0) s_wmax[tid >> 6] = v;
    }
    {   // LUT for this batch: 325 contiguous half2
        const __half2* lutg = (const __half2*)((const __half*)(ws + 1024)
                                               + (size_t)b0 * NKNOT * NC);
        for (int i = tid; i < NKNOT * 5; i += 256) s_luth[i] = lutg[i];
    }
    // softmax(solver_params)
    float p0 = solver[0], p1 = solver[1], p2 = solver[2];
    float pm = fmaxf(p0, fmaxf(p1, p2));
    float e0 = expf(p0 - pm), e1 = expf(p1 - pm), e2 = expf(p2 - pm);
    float inv = 1.f / (e0 + e1 + e2);
    float w0 = e0 * inv, w1 = e1 * inv, w2 = e2 * inv;

    const float g0 = 0.274068619f, g1 = 0.451862761f;
    const bool do_smooth = (w2 > 0.1f);

    float gmax, k0, potscale;   // set after first barrier

    #pragma unroll 1
    for (int sub = 0; sub < 2; sub++) {
        const int tile_x = tile_x_base + sub * 16;

        if (sub == 1) __syncthreads();  // prior tile's s_met2 readers done

        // mass tile 24x24 (12 float2/row; gx even -> pair all-in or all-out)
        {
            const float* massb = mass + (size_t)b0 * GH * GW;
            for (int i = tid; i < 24 * 12; i += 256) {
                int my = i / 12, jx = i % 12;
                int gy = tile_y - 4 + my, gx = tile_x - 4 + 2 * jx;
                float2 v = make_float2(0.f, 0.f);
                if ((unsigned)gy < GH && (unsigned)gx < GW)
                    v = *(const float2*)(massb + gy * GW + gx);
                *(float2*)&s_mass[my][2 * jx] = v;
            }
        }
        __syncthreads();

        if (sub == 0) {
            gmax = fmaxf(fmaxf(s_wmax[0], s_wmax[1]), fmaxf(s_wmax[2], s_wmax[3]));
            k0 = -25.132741228718345f * w0;          // w0 * (-8*pi*G/c^4)
            potscale = 2.f * w1 / (gmax + 1e-8f);    // folds mass normalization
        }

        // --- stage 2: one region pixel per item (324 items, balanced) ---
        for (int idx = tid; idx < 18 * 18; idx += 256) {
            const int ry = idx / 18, rx = idx % 18;
            const int gy = tile_y + ry - 1, gx = tile_x + rx - 1;
            if ((unsigned)gy >= GH || (unsigned)gx >= GW) {
                #pragma unroll
                for (int cp = 0; cp < 5; cp++)
                    s_met2[cp][ry][rx] = make_float2(0.f, 0.f);  // zero pad
                continue;
            }
            const int cy = ry + 3, cx = rx + 3;
            const float m = s_mass[cy][cx];
            // 7x7 Green conv, symmetric-paired: w(dy,dx) == w(-dy,-dx)
            float pot = 0.f;
            #pragma unroll
            for (int dy = 0; dy <= 3; dy++) {
                #pragma unroll
                for (int dx = -3; dx <= 3; dx++) {
                    if (dy == 0 && dx <= 0) continue;
                    const float wgt = -0.15915494309189535f /
                                      __builtin_sqrtf((float)(dy * dy + dx * dx));
                    pot += wgt * (s_mass[cy + dy][cx + dx] + s_mass[cy - dy][cx - dx]);
                }
            }
            const float potterm = potscale * pot;
            // fp16 LUT lerp (65 knots, spacing 1/64)
            float x = m * 64.f;
            int i0 = (int)x;
            i0 = i0 < 63 ? i0 : 63;
            const float f = x - (float)i0;
            const __half2* L0 = &s_luth[i0 * 5];
            const float2* mi2 = (const float2*)(minit + ((size_t)(b0 * GH + gy) * GW + gx) * NC);
            #pragma unroll
            for (int cp = 0; cp < 5; cp++) {
                float2 t0 = __half22float2(L0[cp]);
                float2 t1 = __half22float2(L0[cp + 5]);
                float2 mi = mi2[cp];
                float2 r;
                r.x = fmaf(k0, fmaf(f, t1.x - t0.x, t0.x), mi.x);
                r.y = fmaf(k0, fmaf(f, t1.y - t0.y, t0.y), mi.y);
                if (cp == 2) r.x += potterm;              // c4
                if (cp == 3) r.y += potterm;              // c7
                if (cp == 0) r.x = fminf(r.x, -0.1f);     // c0
                if (cp == 2) r.x = fmaxf(r.x, 0.1f);      // c4
                if (cp == 3) r.y = fmaxf(r.y, 0.1f);      // c7
                if (cp == 4) r.y = fmaxf(r.y, 0.1f);      // c9
                s_met2[cp][ry][rx] = r;
            }
        }
        __syncthreads();

        // --- stage 3: per-thread pixel, 3x3 smooth, direct strided store ---
        {
            const int oy = tid >> 4, ox = tid & 15;
            const int gy = tile_y + oy, gx = tile_x + ox;
            float2* outp2 = (float2*)(out + ((size_t)(b0 * GH + gy) * GW + gx) * NC);
            #pragma unroll
            for (int cp = 0; cp < 5; cp++) {
                float2 v;
                if (do_smooth) {
                    float2 a0 = s_met2[cp][oy][ox],      a1 = s_met2[cp][oy][ox + 1],      a2 = s_met2[cp][oy][ox + 2];
                    float2 b0v = s_met2[cp][oy + 1][ox], b1 = s_met2[cp][oy + 1][ox + 1], b2 = s_met2[cp][oy + 1][ox + 2];
                    float2 c0 = s_met2[cp][oy + 2][ox],  c1 = s_met2[cp][oy + 2][ox + 1], c2 = s_met2[cp][oy + 2][ox + 2];
                    float r0x = fmaf(g0, a0.x + a2.x, g1 * a1.x);
                    float r0y = fmaf(g0, a0.y + a2.y, g1 * a1.y);
                    float r1x = fmaf(g0, b0v.x + b2.x, g1 * b1.x);
                    float r1y = fmaf(g0, b0v.y + b2.y, g1 * b1.y);
                    float r2x = fmaf(g0, c0.x + c2.x, g1 * c1.x);
                    float r2y = fmaf(g0, c0.y + c2.y, g1 * c1.y);
                    v.x = fmaf(g0, r0x + r2x, g1 * r1x);
                    v.y = fmaf(g0, r0y + r2y, g1 * r1y);
                } else {
                    v = s_met2[cp][oy + 1][ox + 1];
                }
                outp2[cp] = v;
            }
        }
    }
}

extern "C" void kernel_launch(void* const* d_in, const int* in_sizes, int n_in,
                              void* d_out, int out_size, void* d_ws, size_t ws_size,
                              hipStream_t stream) {
    const float* mass   = (const float*)d_in[0];
    const float* vel    = (const float*)d_in[1];
    const float* minit  = (const float*)d_in[2];
    const float* e_w1   = (const float*)d_in[3];
    const float* e_b1   = (const float*)d_in[4];
    const float* e_w2   = (const float*)d_in[5];
    const float* e_b2   = (const float*)d_in[6];
    const float* m_w1   = (const float*)d_in[7];
    const float* m_b1   = (const float*)d_in[8];
    const float* m_w2   = (const float*)d_in[9];
    const float* m_b2   = (const float*)d_in[10];
    const float* s_w1   = (const float*)d_in[11];
    const float* s_b1   = (const float*)d_in[12];
    const float* s_w2   = (const float*)d_in[13];
    const float* s_b2   = (const float*)d_in[14];
    const float* solver = (const float*)d_in[15];
    float* ws  = (float*)d_ws;
    float* out = (float*)d_out;

    k_pre<<<386, 256, 0, stream>>>(mass, vel, e_w1, e_b1, e_w2, e_b2,
                                   m_w1, m_b1, m_w2, m_b2,
                                   s_w1, s_b1, s_w2, s_b2, ws);
    // Decomposition measurement: k_main twice (identical work, identical
    // output; deterministic). k_main_dur ~= this_round_dur - 27.0 - gap.
    k_main<<<1024, 256, 0, stream>>>(mass, minit, solver, ws, out);
    k_main<<<1024, 256, 0, stream>>>(mass, minit, solver, ws, out);
}

// Round 13
// 26.044 us; speedup vs baseline: 1.6709x; 1.6709x over previous
//
#include <hip/hip_runtime.h>
#include <hip/hip_fp16.h>
#include <math.h>

// Problem: B=8, H=W=256, C=10 metric channels, all fp32.
// ws layout: float[0..255] = per-block partial maxes of mass;
//            half[] at ws+1024 floats: 8*65*10 LUT of T(mass), stride 10.
#define GH 256
#define GW 256
#define NC 10
#define NKNOT 65   // knots at m = k/64, k=0..64 (covers mass in [0,1])

__device__ __forceinline__ float gelu_exact(float x) {
    return 0.5f * x * (1.0f + erff(x * 0.70710678118654752f));
}
__device__ __forceinline__ float softplus_f(float x) {
    if (x > 20.f) return x;
    return log1pf(expf(x));
}

// ---- Kernel 1: blocks 0..129 build LUT (one wave per (batch,knot), 520 waves);
//      blocks 130..385 compute partial max of mass (float4 loads).
__global__ __launch_bounds__(256) void k_pre(
        const float* __restrict__ mass,
        const float* __restrict__ vel,
        const float* __restrict__ e_w1, const float* __restrict__ e_b1,
        const float* __restrict__ e_w2, const float* __restrict__ e_b2,
        const float* __restrict__ m_w1, const float* __restrict__ m_b1,
        const float* __restrict__ m_w2, const float* __restrict__ m_b2,
        const float* __restrict__ s_w1, const float* __restrict__ s_b1,
        const float* __restrict__ s_w2, const float* __restrict__ s_b2,
        float* __restrict__ ws) {
    const int tid = threadIdx.x;
    if (blockIdx.x >= 130) {  // ---- partial max over mass
        const int pb = blockIdx.x - 130;           // 0..255
        const float4* mass4 = (const float4*)mass; // 131072 float4 total
        int base = pb * 512 + tid;                 // 512 float4 per block
        float4 a = mass4[base];
        float4 c = mass4[base + 256];
        float v = fmaxf(fmaxf(fmaxf(a.x, a.y), fmaxf(a.z, a.w)),
                        fmaxf(fmaxf(c.x, c.y), fmaxf(c.z, c.w)));
        #pragma unroll
        for (int off = 32; off > 0; off >>= 1)
            v = fmaxf(v, __shfl_xor(v, off, 64));
        __shared__ float sred[4];
        if ((tid & 63) == 0) sred[tid >> 6] = v;
        __syncthreads();
        if (tid == 0)
            ws[pb] = fmaxf(fmaxf(sred[0], sred[1]), fmaxf(sred[2], sred[3]));
        return;
    }
    // ---- LUT build: wave-parallel over hidden dim
    const int wave = blockIdx.x * 4 + (tid >> 6);   // 0..519 == 8*65-1
    const int lane = tid & 63;
    if (wave >= 8 * NKNOT) return;
    const int b = wave / NKNOT, knot = wave % NKNOT;
    const float m = (float)knot * (1.0f / 64.0f);
    const float vx = vel[b * 3 + 0], vy = vel[b * 3 + 1], vz = vel[b * 3 + 2];

    float acc[10];
    {   // energy hidden unit `lane`
        float pre = m * e_w1[lane] + vx * e_w1[64 + lane] + vy * e_w1[128 + lane]
                  + vz * e_w1[192 + lane] + e_b1[lane];
        acc[0] = gelu_exact(pre) * e_w2[lane];
    }
    {   // momentum hidden unit `lane`
        float pre = m * m_w1[lane] + vx * m_w1[64 + lane] + vy * m_w1[128 + lane]
                  + vz * m_w1[192 + lane] + m_b1[lane];
        float h = gelu_exact(pre);
        acc[1] = h * m_w2[lane * 3 + 0];
        acc[2] = h * m_w2[lane * 3 + 1];
        acc[3] = h * m_w2[lane * 3 + 2];
    }
    {   // stress hidden units `lane`, `lane+64`
        float pre0 = m * s_w1[lane] + vx * s_w1[128 + lane] + vy * s_w1[256 + lane]
                   + vz * s_w1[384 + lane] + s_b1[lane];
        float pre1 = m * s_w1[64 + lane] + vx * s_w1[192 + lane] + vy * s_w1[320 + lane]
                   + vz * s_w1[448 + lane] + s_b1[64 + lane];
        float h0 = gelu_exact(pre0), h1 = gelu_exact(pre1);
        #pragma unroll
        for (int k = 0; k < 6; k++)
            acc[4 + k] = h0 * s_w2[lane * 6 + k] + h1 * s_w2[(lane + 64) * 6 + k];
    }
    #pragma unroll
    for (int c = 0; c < 10; c++) {
        float v = acc[c];
        #pragma unroll
        for (int off = 32; off > 0; off >>= 1)
            v += __shfl_xor(v, off, 64);
        acc[c] = v;
    }
    if (lane == 0) {
        __half* lut = (__half*)(ws + 1024) + (size_t)(b * NKNOT + knot) * NC;
        lut[0] = __float2half_rn(softplus_f(acc[0] + e_b2[0]));
        lut[1] = __float2half_rn(acc[1] + m_b2[0]);
        lut[2] = __float2half_rn(acc[2] + m_b2[1]);
        lut[3] = __float2half_rn(acc[3] + m_b2[2]);
        #pragma unroll
        for (int k = 0; k < 6; k++)
            lut[4 + k] = __float2half_rn(acc[4 + k] + s_b2[k]);
    }
}

// ---- Kernel 2: one 16x16 tile per block, 2048 blocks, 8 blocks/CU resident
// (32 waves/CU, full occupancy). Inner pipeline identical to the 27.0µs best.
__global__ __launch_bounds__(256, 8) void k_main(const float* __restrict__ mass,
                                                 const float* __restrict__ minit,
                                                 const float* __restrict__ solver,
                                                 const float* __restrict__ ws,
                                                 float* __restrict__ out) {
    const int tid = threadIdx.x;
    const int bid = blockIdx.x;               // 0..2047
    const int b0 = bid >> 8;                  // batch
    const int ti = bid & 255;                 // tile index within batch
    const int tile_y = (ti >> 4) * 16;
    const int tile_x = (ti & 15) * 16;

    __shared__ float   s_mass[24][24];                 // 2.3 KB, halo 4
    __shared__ __half2 s_luth[NKNOT * 5];              // 1.3 KB
    __shared__ __align__(16) float2 s_met2[5][18][18]; // 13.0 KB, halo 1
    __shared__ float   s_wmax[4];

    // --- phase 0 ---
    {   // finalize global max (256 partials, 1/thread)
        float v = ws[tid];
        #pragma unroll
        for (int off = 32; off > 0; off >>= 1)
            v = fmaxf(v, __shfl_xor(v, off, 64));
        if ((tid & 63) == 0) s_wmax[tid >> 6] = v;
    }
    {   // LUT for this batch: 325 contiguous half2
        const __half2* lutg = (const __half2*)((const __half*)(ws + 1024)
                                               + (size_t)b0 * NKNOT * NC);
        for (int i = tid; i < NKNOT * 5; i += 256) s_luth[i] = lutg[i];
    }
    {   // mass tile 24x24 (12 float2/row; gx even -> pair all-in or all-out)
        const float* massb = mass + (size_t)b0 * GH * GW;
        for (int i = tid; i < 24 * 12; i += 256) {
            int my = i / 12, jx = i % 12;
            int gy = tile_y - 4 + my, gx = tile_x - 4 + 2 * jx;
            float2 v = make_float2(0.f, 0.f);
            if ((unsigned)gy < GH && (unsigned)gx < GW)
                v = *(const float2*)(massb + gy * GW + gx);
            *(float2*)&s_mass[my][2 * jx] = v;
        }
    }
    // softmax(solver_params)
    float p0 = solver[0], p1 = solver[1], p2 = solver[2];
    float pm = fmaxf(p0, fmaxf(p1, p2));
    float e0 = expf(p0 - pm), e1 = expf(p1 - pm), e2 = expf(p2 - pm);
    float inv = 1.f / (e0 + e1 + e2);
    float w0 = e0 * inv, w1 = e1 * inv, w2 = e2 * inv;

    __syncthreads();

    const float gmax = fmaxf(fmaxf(s_wmax[0], s_wmax[1]), fmaxf(s_wmax[2], s_wmax[3]));
    const float k0 = -25.132741228718345f * w0;          // w0 * (-8*pi*G/c^4)
    const float potscale = 2.f * w1 / (gmax + 1e-8f);    // folds mass normalization

    // --- stage 2: one region pixel per item (324 items, balanced) ---
    for (int idx = tid; idx < 18 * 18; idx += 256) {
        const int ry = idx / 18, rx = idx % 18;
        const int gy = tile_y + ry - 1, gx = tile_x + rx - 1;
        if ((unsigned)gy >= GH || (unsigned)gx >= GW) {
            #pragma unroll
            for (int cp = 0; cp < 5; cp++)
                s_met2[cp][ry][rx] = make_float2(0.f, 0.f);  // zero pad
            continue;
        }
        const int cy = ry + 3, cx = rx + 3;
        const float m = s_mass[cy][cx];
        // 7x7 Green conv, symmetric-paired: w(dy,dx) == w(-dy,-dx)
        float pot = 0.f;
        #pragma unroll
        for (int dy = 0; dy <= 3; dy++) {
            #pragma unroll
            for (int dx = -3; dx <= 3; dx++) {
                if (dy == 0 && dx <= 0) continue;
                const float wgt = -0.15915494309189535f /
                                  __builtin_sqrtf((float)(dy * dy + dx * dx));
                pot += wgt * (s_mass[cy + dy][cx + dx] + s_mass[cy - dy][cx - dx]);
            }
        }
        const float potterm = potscale * pot;
        // fp16 LUT lerp (65 knots, spacing 1/64)
        float x = m * 64.f;
        int i0 = (int)x;
        i0 = i0 < 63 ? i0 : 63;
        const float f = x - (float)i0;
        const __half2* L0 = &s_luth[i0 * 5];
        const float2* mi2 = (const float2*)(minit + ((size_t)(b0 * GH + gy) * GW + gx) * NC);
        #pragma unroll
        for (int cp = 0; cp < 5; cp++) {
            float2 t0 = __half22float2(L0[cp]);
            float2 t1 = __half22float2(L0[cp + 5]);
            float2 mi = mi2[cp];
            float2 r;
            r.x = fmaf(k0, fmaf(f, t1.x - t0.x, t0.x), mi.x);
            r.y = fmaf(k0, fmaf(f, t1.y - t0.y, t0.y), mi.y);
            if (cp == 2) r.x += potterm;              // c4
            if (cp == 3) r.y += potterm;              // c7
            if (cp == 0) r.x = fminf(r.x, -0.1f);     // c0
            if (cp == 2) r.x = fmaxf(r.x, 0.1f);      // c4
            if (cp == 3) r.y = fmaxf(r.y, 0.1f);      // c7
            if (cp == 4) r.y = fmaxf(r.y, 0.1f);      // c9
            s_met2[cp][ry][rx] = r;
        }
    }
    __syncthreads();

    // --- stage 3: per-thread pixel, 3x3 smooth, direct strided store ---
    {
        const float g0 = 0.274068619f, g1 = 0.451862761f;
        const bool do_smooth = (w2 > 0.1f);
        const int oy = tid >> 4, ox = tid & 15;
        const int gy = tile_y + oy, gx = tile_x + ox;
        float2* outp2 = (float2*)(out + ((size_t)(b0 * GH + gy) * GW + gx) * NC);
        #pragma unroll
        for (int cp = 0; cp < 5; cp++) {
            float2 v;
            if (do_smooth) {
                float2 a0 = s_met2[cp][oy][ox],      a1 = s_met2[cp][oy][ox + 1],      a2 = s_met2[cp][oy][ox + 2];
                float2 b0v = s_met2[cp][oy + 1][ox], b1 = s_met2[cp][oy + 1][ox + 1], b2 = s_met2[cp][oy + 1][ox + 2];
                float2 c0 = s_met2[cp][oy + 2][ox],  c1 = s_met2[cp][oy + 2][ox + 1], c2 = s_met2[cp][oy + 2][ox + 2];
                float r0x = fmaf(g0, a0.x + a2.x, g1 * a1.x);
                float r0y = fmaf(g0, a0.y + a2.y, g1 * a1.y);
                float r1x = fmaf(g0, b0v.x + b2.x, g1 * b1.x);
                float r1y = fmaf(g0, b0v.y + b2.y, g1 * b1.y);
                float r2x = fmaf(g0, c0.x + c2.x, g1 * c1.x);
                float r2y = fmaf(g0, c0.y + c2.y, g1 * c1.y);
                v.x = fmaf(g0, r0x + r2x, g1 * r1x);
                v.y = fmaf(g0, r0y + r2y, g1 * r1y);
            } else {
                v = s_met2[cp][oy + 1][ox + 1];
            }
            outp2[cp] = v;
        }
    }
}

extern "C" void kernel_launch(void* const* d_in, const int* in_sizes, int n_in,
                              void* d_out, int out_size, void* d_ws, size_t ws_size,
                              hipStream_t stream) {
    const float* mass   = (const float*)d_in[0];
    const float* vel    = (const float*)d_in[1];
    const float* minit  = (const float*)d_in[2];
    const float* e_w1   = (const float*)d_in[3];
    const float* e_b1   = (const float*)d_in[4];
    const float* e_w2   = (const float*)d_in[5];
    const float* e_b2   = (const float*)d_in[6];
    const float* m_w1   = (const float*)d_in[7];
    const float* m_b1   = (const float*)d_in[8];
    const float* m_w2   = (const float*)d_in[9];
    const float* m_b2   = (const float*)d_in[10];
    const float* s_w1   = (const float*)d_in[11];
    const float* s_b1   = (const float*)d_in[12];
    const float* s_w2   = (const float*)d_in[13];
    const float* s_b2   = (const float*)d_in[14];
    const float* solver = (const float*)d_in[15];
    float* ws  = (float*)d_ws;
    float* out = (float*)d_out;

    k_pre<<<386, 256, 0, stream>>>(mass, vel, e_w1, e_b1, e_w2, e_b2,
                                   m_w1, m_b1, m_w2, m_b2,
                                   s_w1, s_b1, s_w2, s_b2, ws);
    k_main<<<2048, 256, 0, stream>>>(mass, minit, solver, ws, out);
}

// Round 14
// 25.942 us; speedup vs baseline: 1.6775x; 1.0039x over previous
//
#include <hip/hip_runtime.h>
#include <hip/hip_fp16.h>
#include <math.h>

// Problem: B=8, H=W=256, C=10 metric channels, all fp32.
// ws layout: float[0..255] = per-block partial maxes of mass;
//            half[] at ws+1024 floats: 8*65*10 LUT of T(mass), stride 10.
#define GH 256
#define GW 256
#define NC 10
#define NKNOT 65   // knots at m = k/64, k=0..64 (covers mass in [0,1])

__device__ __forceinline__ float gelu_exact(float x) {
    return 0.5f * x * (1.0f + erff(x * 0.70710678118654752f));
}
__device__ __forceinline__ float softplus_f(float x) {
    if (x > 20.f) return x;
    return log1pf(expf(x));
}

// ---- Kernel 1: blocks 0..129 build LUT (one wave per (batch,knot), 520 waves);
//      blocks 130..385 compute partial max of mass (float4 loads).
__global__ __launch_bounds__(256) void k_pre(
        const float* __restrict__ mass,
        const float* __restrict__ vel,
        const float* __restrict__ e_w1, const float* __restrict__ e_b1,
        const float* __restrict__ e_w2, const float* __restrict__ e_b2,
        const float* __restrict__ m_w1, const float* __restrict__ m_b1,
        const float* __restrict__ m_w2, const float* __restrict__ m_b2,
        const float* __restrict__ s_w1, const float* __restrict__ s_b1,
        const float* __restrict__ s_w2, const float* __restrict__ s_b2,
        float* __restrict__ ws) {
    const int tid = threadIdx.x;
    if (blockIdx.x >= 130) {  // ---- partial max over mass
        const int pb = blockIdx.x - 130;           // 0..255
        const float4* mass4 = (const float4*)mass; // 131072 float4 total
        int base = pb * 512 + tid;                 // 512 float4 per block
        float4 a = mass4[base];
        float4 c = mass4[base + 256];
        float v = fmaxf(fmaxf(fmaxf(a.x, a.y), fmaxf(a.z, a.w)),
                        fmaxf(fmaxf(c.x, c.y), fmaxf(c.z, c.w)));
        #pragma unroll
        for (int off = 32; off > 0; off >>= 1)
            v = fmaxf(v, __shfl_xor(v, off, 64));
        __shared__ float sred[4];
        if ((tid & 63) == 0) sred[tid >> 6] = v;
        __syncthreads();
        if (tid == 0)
            ws[pb] = fmaxf(fmaxf(sred[0], sred[1]), fmaxf(sred[2], sred[3]));
        return;
    }
    // ---- LUT build: wave-parallel over hidden dim
    const int wave = blockIdx.x * 4 + (tid >> 6);   // 0..519 == 8*65-1
    const int lane = tid & 63;
    if (wave >= 8 * NKNOT) return;
    const int b = wave / NKNOT, knot = wave % NKNOT;
    const float m = (float)knot * (1.0f / 64.0f);
    const float vx = vel[b * 3 + 0], vy = vel[b * 3 + 1], vz = vel[b * 3 + 2];

    float acc[10];
    {   // energy hidden unit `lane`
        float pre = m * e_w1[lane] + vx * e_w1[64 + lane] + vy * e_w1[128 + lane]
                  + vz * e_w1[192 + lane] + e_b1[lane];
        acc[0] = gelu_exact(pre) * e_w2[lane];
    }
    {   // momentum hidden unit `lane`
        float pre = m * m_w1[lane] + vx * m_w1[64 + lane] + vy * m_w1[128 + lane]
                  + vz * m_w1[192 + lane] + m_b1[lane];
        float h = gelu_exact(pre);
        acc[1] = h * m_w2[lane * 3 + 0];
        acc[2] = h * m_w2[lane * 3 + 1];
        acc[3] = h * m_w2[lane * 3 + 2];
    }
    {   // stress hidden units `lane`, `lane+64`
        float pre0 = m * s_w1[lane] + vx * s_w1[128 + lane] + vy * s_w1[256 + lane]
                   + vz * s_w1[384 + lane] + s_b1[lane];
        float pre1 = m * s_w1[64 + lane] + vx * s_w1[192 + lane] + vy * s_w1[320 + lane]
                   + vz * s_w1[448 + lane] + s_b1[64 + lane];
        float h0 = gelu_exact(pre0), h1 = gelu_exact(pre1);
        #pragma unroll
        for (int k = 0; k < 6; k++)
            acc[4 + k] = h0 * s_w2[lane * 6 + k] + h1 * s_w2[(lane + 64) * 6 + k];
    }
    #pragma unroll
    for (int c = 0; c < 10; c++) {
        float v = acc[c];
        #pragma unroll
        for (int off = 32; off > 0; off >>= 1)
            v += __shfl_xor(v, off, 64);
        acc[c] = v;
    }
    if (lane == 0) {
        __half* lut = (__half*)(ws + 1024) + (size_t)(b * NKNOT + knot) * NC;
        lut[0] = __float2half_rn(softplus_f(acc[0] + e_b2[0]));
        lut[1] = __float2half_rn(acc[1] + m_b2[0]);
        lut[2] = __float2half_rn(acc[2] + m_b2[1]);
        lut[3] = __float2half_rn(acc[3] + m_b2[2]);
        #pragma unroll
        for (int k = 0; k < 6; k++)
            lut[4 + k] = __float2half_rn(acc[4 + k] + s_b2[k]);
    }
}

// ---- Kernel 2: one 16x16 tile per block, 2048 blocks, 8 blocks/CU (32 w/CU).
// LDS-lean pipeline: |dy|-plane decomposed Green conv + fp16 met planes.
__global__ __launch_bounds__(256, 8) void k_main(const float* __restrict__ mass,
                                                 const float* __restrict__ minit,
                                                 const float* __restrict__ solver,
                                                 const float* __restrict__ ws,
                                                 float* __restrict__ out) {
    const int tid = threadIdx.x;
    const int bid = blockIdx.x;               // 0..2047
    const int b0 = bid >> 8;                  // batch
    const int ti = bid & 255;                 // tile index within batch
    const int tile_y = (ti >> 4) * 16;
    const int tile_x = (ti & 15) * 16;

    __shared__ float   s_mass[24][24];        // 2.3 KB, halo 4
    __shared__ float   s_H[4][24][18];        // 6.8 KB horizontal Green convs
    __shared__ __half2 s_luth[NKNOT * 5];     // 1.3 KB
    __shared__ __half2 s_meth[5][18][18];     // 6.3 KB fp16 met planes
    __shared__ float   s_wmax[4];

    // --- phase 0 ---
    {   // finalize global max (256 partials, 1/thread)
        float v = ws[tid];
        #pragma unroll
        for (int off = 32; off > 0; off >>= 1)
            v = fmaxf(v, __shfl_xor(v, off, 64));
        if ((tid & 63) == 0) s_wmax[tid >> 6] = v;
    }
    {   // LUT for this batch: 325 contiguous half2
        const __half2* lutg = (const __half2*)((const __half*)(ws + 1024)
                                               + (size_t)b0 * NKNOT * NC);
        for (int i = tid; i < NKNOT * 5; i += 256) s_luth[i] = lutg[i];
    }
    {   // mass tile 24x24 (12 float2/row; gx even -> pair all-in or all-out)
        const float* massb = mass + (size_t)b0 * GH * GW;
        for (int i = tid; i < 24 * 12; i += 256) {
            int my = i / 12, jx = i % 12;
            int gy = tile_y - 4 + my, gx = tile_x - 4 + 2 * jx;
            float2 v = make_float2(0.f, 0.f);
            if ((unsigned)gy < GH && (unsigned)gx < GW)
                v = *(const float2*)(massb + gy * GW + gx);
            *(float2*)&s_mass[my][2 * jx] = v;
        }
    }
    // softmax(solver_params)
    float p0 = solver[0], p1 = solver[1], p2 = solver[2];
    float pm = fmaxf(p0, fmaxf(p1, p2));
    float e0 = expf(p0 - pm), e1 = expf(p1 - pm), e2 = expf(p2 - pm);
    float inv = 1.f / (e0 + e1 + e2);
    float w0 = e0 * inv, w1 = e1 * inv, w2 = e2 * inv;

    __syncthreads();

    const float gmax = fmaxf(fmaxf(s_wmax[0], s_wmax[1]), fmaxf(s_wmax[2], s_wmax[3]));
    const float k0 = -25.132741228718345f * w0;          // w0 * (-8*pi*G/c^4)
    const float potscale = 2.f * w1 / (gmax + 1e-8f);    // folds mass normalization

    // Green weights: GWt[|dy|][|dx|] = -1/(2*pi*r), GWt[0][0] = 0
    const float GWt[4][4] = {
        {0.f,          -0.15915494f, -0.07957747f, -0.05305165f},
        {-0.15915494f, -0.11253954f, -0.07117625f, -0.05033165f},
        {-0.07957747f, -0.07117625f, -0.05626977f, -0.04414183f},
        {-0.05305165f, -0.05033165f, -0.04414183f, -0.03751318f}};

    // --- phase A: 4 horizontal 7-tap convs (one per |dy|) over 24x18 ---
    for (int it = tid; it < 24 * 18; it += 256) {
        const int y = it / 18, x = it % 18;   // x -> mass col cx = x+3
        float m0 = s_mass[y][x],     m1 = s_mass[y][x + 1], m2 = s_mass[y][x + 2];
        float m3 = s_mass[y][x + 3], m4 = s_mass[y][x + 4], m5 = s_mass[y][x + 5];
        float m6 = s_mass[y][x + 6];
        const float p06 = m0 + m6, p15 = m1 + m5, p24 = m2 + m4;
        #pragma unroll
        for (int a = 0; a < 4; a++) {
            float h = GWt[a][3] * p06;
            h = fmaf(GWt[a][2], p15, h);
            h = fmaf(GWt[a][1], p24, h);
            h = fmaf(GWt[a][0], m3, h);     // a=0: weight 0 kills center tap
            s_H[a][y][x] = h;
        }
    }
    __syncthreads();

    // --- stage 2: one region pixel per item; pot = 7 vertical H adds ---
    for (int idx = tid; idx < 18 * 18; idx += 256) {
        const int ry = idx / 18, rx = idx % 18;
        const int gy = tile_y + ry - 1, gx = tile_x + rx - 1;
        if ((unsigned)gy >= GH || (unsigned)gx >= GW) {
            #pragma unroll
            for (int cp = 0; cp < 5; cp++)
                s_meth[cp][ry][rx] = __floats2half2_rn(0.f, 0.f);  // zero pad
            continue;
        }
        const float m = s_mass[ry + 3][rx + 3];
        float pot = s_H[3][ry][rx] + s_H[2][ry + 1][rx] + s_H[1][ry + 2][rx]
                  + s_H[0][ry + 3][rx]
                  + s_H[1][ry + 4][rx] + s_H[2][ry + 5][rx] + s_H[3][ry + 6][rx];
        const float potterm = potscale * pot;
        // fp16 LUT lerp (65 knots, spacing 1/64)
        float x = m * 64.f;
        int i0 = (int)x;
        i0 = i0 < 63 ? i0 : 63;
        const float f = x - (float)i0;
        const __half2* L0 = &s_luth[i0 * 5];
        const float2* mi2 = (const float2*)(minit + ((size_t)(b0 * GH + gy) * GW + gx) * NC);
        #pragma unroll
        for (int cp = 0; cp < 5; cp++) {
            float2 t0 = __half22float2(L0[cp]);
            float2 t1 = __half22float2(L0[cp + 5]);
            float2 mi = mi2[cp];
            float2 r;
            r.x = fmaf(k0, fmaf(f, t1.x - t0.x, t0.x), mi.x);
            r.y = fmaf(k0, fmaf(f, t1.y - t0.y, t0.y), mi.y);
            if (cp == 2) r.x += potterm;              // c4
            if (cp == 3) r.y += potterm;              // c7
            if (cp == 0) r.x = fminf(r.x, -0.1f);     // c0
            if (cp == 2) r.x = fmaxf(r.x, 0.1f);      // c4
            if (cp == 3) r.y = fmaxf(r.y, 0.1f);      // c7
            if (cp == 4) r.y = fmaxf(r.y, 0.1f);      // c9
            s_meth[cp][ry][rx] = __floats2half2_rn(r.x, r.y);
        }
    }
    __syncthreads();

    // --- stage 3: per-thread pixel, 3x3 smooth (fp16 reads), strided store ---
    {
        const float g0 = 0.274068619f, g1 = 0.451862761f;
        const bool do_smooth = (w2 > 0.1f);
        const int oy = tid >> 4, ox = tid & 15;
        const int gy = tile_y + oy, gx = tile_x + ox;
        float2* outp2 = (float2*)(out + ((size_t)(b0 * GH + gy) * GW + gx) * NC);
        #pragma unroll
        for (int cp = 0; cp < 5; cp++) {
            float2 v;
            if (do_smooth) {
                float2 a0 = __half22float2(s_meth[cp][oy][ox]);
                float2 a1 = __half22float2(s_meth[cp][oy][ox + 1]);
                float2 a2 = __half22float2(s_meth[cp][oy][ox + 2]);
                float2 b0v = __half22float2(s_meth[cp][oy + 1][ox]);
                float2 b1 = __half22float2(s_meth[cp][oy + 1][ox + 1]);
                float2 b2 = __half22float2(s_meth[cp][oy + 1][ox + 2]);
                float2 c0 = __half22float2(s_meth[cp][oy + 2][ox]);
                float2 c1 = __half22float2(s_meth[cp][oy + 2][ox + 1]);
                float2 c2 = __half22float2(s_meth[cp][oy + 2][ox + 2]);
                float r0x = fmaf(g0, a0.x + a2.x, g1 * a1.x);
                float r0y = fmaf(g0, a0.y + a2.y, g1 * a1.y);
                float r1x = fmaf(g0, b0v.x + b2.x, g1 * b1.x);
                float r1y = fmaf(g0, b0v.y + b2.y, g1 * b1.y);
                float r2x = fmaf(g0, c0.x + c2.x, g1 * c1.x);
                float r2y = fmaf(g0, c0.y + c2.y, g1 * c1.y);
                v.x = fmaf(g0, r0x + r2x, g1 * r1x);
                v.y = fmaf(g0, r0y + r2y, g1 * r1y);
            } else {
                v = __half22float2(s_meth[cp][oy + 1][ox + 1]);
            }
            outp2[cp] = v;
        }
    }
}

extern "C" void kernel_launch(void* const* d_in, const int* in_sizes, int n_in,
                              void* d_out, int out_size, void* d_ws, size_t ws_size,
                              hipStream_t stream) {
    const float* mass   = (const float*)d_in[0];
    const float* vel    = (const float*)d_in[1];
    const float* minit  = (const float*)d_in[2];
    const float* e_w1   = (const float*)d_in[3];
    const float* e_b1   = (const float*)d_in[4];
    const float* e_w2   = (const float*)d_in[5];
    const float* e_b2   = (const float*)d_in[6];
    const float* m_w1   = (const float*)d_in[7];
    const float* m_b1   = (const float*)d_in[8];
    const float* m_w2   = (const float*)d_in[9];
    const float* m_b2   = (const float*)d_in[10];
    const float* s_w1   = (const float*)d_in[11];
    const float* s_b1   = (const float*)d_in[12];
    const float* s_w2   = (const float*)d_in[13];
    const float* s_b2   = (const float*)d_in[14];
    const float* solver = (const float*)d_in[15];
    float* ws  = (float*)d_ws;
    float* out = (float*)d_out;

    k_pre<<<386, 256, 0, stream>>>(mass, vel, e_w1, e_b1, e_w2, e_b2,
                                   m_w1, m_b1, m_w2, m_b2,
                                   s_w1, s_b1, s_w2, s_b2, ws);
    k_main<<<2048, 256, 0, stream>>>(mass, minit, solver, ws, out);
}